// Round 1
// baseline (1111.332 us; speedup 1.0000x reference)
//
#include <hip/hip_runtime.h>

// clusteringEMA: B=65536, D=512, K=1024, C=100
// Inputs: 0 batch_vectors f32[B,D], 1 batch_keys_id i32[B], 2 weight f32[D,K],
//         3 cluster_size f32[K], 4 embed_avg f32[D,K], 5 hist f32[K,C]
// Outputs (flat f32): new_weight[D*K], new_cluster_size[K], new_embed_avg[D*K],
//                     new_hist[K*C], argmin[B] (as float)

#define NB 65536
#define ND 512
#define NK 1024
#define NC 100

// ---------------- ws layout (element offsets, all 4-byte) ----------------
// zeroed region: [0 .. OFF_ZERO_END)
#define OFF_COUNTS   0          // int [1024]
#define OFF_CURSOR   1024       // int [1024]
#define OFF_BHIST    2048       // float [102400]
#define OFF_WSQ      104448     // float [1024]
#define OFF_ESUM     105472     // float [1024*512]
#define OFF_ZERO_END 629760
#define OFF_CSNORM   629760     // float [1024]
#define OFF_OFFSETS  630784     // int [1024]
#define OFF_ARGMIN   631808     // int [65536]
#define OFF_ORDER    697344     // int [65536]

// ---------------- kernel 1: w_sq[k] = sum_d W[d][k]^2 ----------------
__global__ __launch_bounds__(256) void wsq_kernel(const float* __restrict__ W,
                                                  float* __restrict__ wsq) {
  int bk = blockIdx.x & 3;       // 4 k-blocks of 256
  int ds = blockIdx.x >> 2;      // 8 d-splits of 64
  int k = bk * 256 + threadIdx.x;
  float s = 0.f;
  int d0 = ds * 64;
#pragma unroll 8
  for (int d = d0; d < d0 + 64; ++d) {
    float w = W[(size_t)d * NK + k];
    s += w * w;
  }
  atomicAdd(&wsq[k], s);
}

// ---------------- kernel 2: fused distance-argmin GEMM ----------------
// block: 256 threads (16 tx x 16 ty), tile BM=128 rows x BN=128 cents, DC=32
// micro-tile 8x8 per thread. val = wsq[c] - 2*dot  (same argmin as sqrt dist)
__global__ __launch_bounds__(256, 2) void argmin_kernel(
    const float* __restrict__ X, const float* __restrict__ W,
    const float* __restrict__ wsq, const int* __restrict__ keys,
    int* __restrict__ argmin_i, float* __restrict__ argmin_f,
    int* __restrict__ counts, float* __restrict__ bhist) {
  __shared__ float Xs[32][132];   // [d][row], transposed; stride 132 -> 2-way banks
  __shared__ float Ws[32][144];   // [d][col], col swizzled: phys = c + 4*(c>>5)
  __shared__ float RedV[128][16];
  __shared__ int   RedI[128][16];

  const int t = threadIdx.x;
  const int tx = t & 15, ty = t >> 4;
  const int brow = blockIdx.x * 128;

  // staging maps
  const int xr = t >> 1, xdb = (t & 1) * 16;       // X: 2 thr/row, 16 floats each
  const int wr = t >> 3, wcb = (t & 7) * 16;       // W: 8 thr/row, 16 floats each
  const int wp = tx * 8 + 4 * (tx >> 2);           // swizzled read col

  float bestV[8];
  int bestI[8];
#pragma unroll
  for (int i = 0; i < 8; ++i) { bestV[i] = 3.4e38f; bestI[i] = 0; }

  for (int kt = 0; kt < 8; ++kt) {
    float acc[8][8];
#pragma unroll
    for (int i = 0; i < 8; ++i)
#pragma unroll
      for (int j = 0; j < 8; ++j) acc[i][j] = 0.f;

    for (int dc = 0; dc < 16; ++dc) {
      // issue global loads (regs) before the barrier
      const float* xg = X + (size_t)(brow + xr) * ND + dc * 32 + xdb;
      const float* wg = W + (size_t)(dc * 32 + wr) * NK + kt * 128 + wcb;
      float4 xa[4], wa[4];
#pragma unroll
      for (int q = 0; q < 4; ++q) xa[q] = *(const float4*)(xg + q * 4);
#pragma unroll
      for (int q = 0; q < 4; ++q) wa[q] = *(const float4*)(wg + q * 4);

      __syncthreads();  // previous compute done reading LDS
#pragma unroll
      for (int q = 0; q < 4; ++q) {
        Xs[xdb + q * 4 + 0][xr] = xa[q].x;
        Xs[xdb + q * 4 + 1][xr] = xa[q].y;
        Xs[xdb + q * 4 + 2][xr] = xa[q].z;
        Xs[xdb + q * 4 + 3][xr] = xa[q].w;
      }
#pragma unroll
      for (int q = 0; q < 4; ++q) {
        int c = wcb + q * 4;
        *(float4*)&Ws[wr][c + 4 * (c >> 5)] = wa[q];
      }
      __syncthreads();

#pragma unroll 4
      for (int kk = 0; kk < 32; ++kk) {
        float4 x0 = *(const float4*)&Xs[kk][ty * 8];
        float4 x1 = *(const float4*)&Xs[kk][ty * 8 + 4];
        float4 w0 = *(const float4*)&Ws[kk][wp];
        float4 w1 = *(const float4*)&Ws[kk][wp + 4];
        float xv[8] = {x0.x, x0.y, x0.z, x0.w, x1.x, x1.y, x1.z, x1.w};
        float wv[8] = {w0.x, w0.y, w0.z, w0.w, w1.x, w1.y, w1.z, w1.w};
#pragma unroll
        for (int i = 0; i < 8; ++i)
#pragma unroll
          for (int j = 0; j < 8; ++j) acc[i][j] += xv[i] * wv[j];
      }
    }

    // epilogue for this k-tile: running argmin (ascending c, strict < = first min)
#pragma unroll
    for (int j = 0; j < 8; ++j) {
      int c = kt * 128 + tx * 8 + j;
      float wq = wsq[c];
#pragma unroll
      for (int i = 0; i < 8; ++i) {
        float v = wq - 2.0f * acc[i][j];
        if (v < bestV[i]) { bestV[i] = v; bestI[i] = c; }
      }
    }
  }

  // cross-thread (tx) reduce per row
#pragma unroll
  for (int i = 0; i < 8; ++i) {
    RedV[ty * 8 + i][tx] = bestV[i];
    RedI[ty * 8 + i][tx] = bestI[i];
  }
  __syncthreads();
  if (t < 128) {
    float bv = RedV[t][0];
    int bi = RedI[t][0];
#pragma unroll
    for (int g = 1; g < 16; ++g) {
      float v = RedV[t][g];
      int ii = RedI[t][g];
      if (v < bv || (v == bv && ii < bi)) { bv = v; bi = ii; }
    }
    int b = brow + t;
    argmin_i[b] = bi;
    argmin_f[b] = (float)bi;
    atomicAdd(&counts[bi], 1);
    atomicAdd(&bhist[(size_t)bi * NC + keys[b]], 1.0f);
  }
}

// ---------------- kernel 3: scan + cluster_size EMA + cs_norm ----------------
__global__ __launch_bounds__(1024) void scan_kernel(
    const int* __restrict__ counts, const float* __restrict__ cluster_size,
    float* __restrict__ out_ncs, float* __restrict__ csnorm,
    int* __restrict__ offsets) {
  __shared__ float sf[1024];
  __shared__ int si[1024];
  int t = threadIdx.x;
  int cnt = counts[t];
  float ncs = cluster_size[t] * 0.99f + 0.01f * (cnt == 0 ? 1.0f : (float)cnt);
  out_ncs[t] = ncs;

  sf[t] = ncs;
  __syncthreads();
  for (int s = 512; s > 0; s >>= 1) {
    if (t < s) sf[t] += sf[t + s];
    __syncthreads();
  }
  float n = sf[0];
  csnorm[t] = (ncs + 1e-5f) / (n + 1024.0f * 1e-5f) * n;

  // exclusive prefix sum of counts (Hillis-Steele)
  si[t] = cnt;
  __syncthreads();
  for (int s = 1; s < 1024; s <<= 1) {
    int v = (t >= s) ? si[t - s] : 0;
    __syncthreads();
    si[t] += v;
    __syncthreads();
  }
  offsets[t] = si[t] - cnt;
}

// ---------------- kernel 4: reorder rows by cluster ----------------
__global__ __launch_bounds__(256) void reorder_kernel(
    const int* __restrict__ argmin_i, const int* __restrict__ offsets,
    int* __restrict__ cursor, int* __restrict__ order) {
  int b = blockIdx.x * 256 + threadIdx.x;
  int k = argmin_i[b];
  int pos = atomicAdd(&cursor[k], 1);
  order[offsets[k] + pos] = b;
}

// ---------------- kernel 5: split gather-sum into esum[K][D] ----------------
#define NSPLIT 8
__global__ __launch_bounds__(256) void gather_kernel(
    const float* __restrict__ X, const int* __restrict__ order,
    const int* __restrict__ offsets, const int* __restrict__ counts,
    float* __restrict__ esum) {
  int k = blockIdx.x >> 3;
  int s = blockIdx.x & 7;
  int cnt = counts[k], start = offsets[k];
  int t = threadIdx.x;
  float a0 = 0.f, a1 = 0.f;
  for (int m = s; m < cnt; m += NSPLIT) {
    int b = order[start + m];
    const float* row = X + (size_t)b * ND;
    a0 += row[t];
    a1 += row[t + 256];
  }
  if (s < cnt) {
    atomicAdd(&esum[(size_t)k * ND + t], a0);
    atomicAdd(&esum[(size_t)k * ND + t + 256], a1);
  }
}

// ---------------- kernel 6: embed_avg EMA + weight (with transpose) ----------
__global__ __launch_bounds__(256) void ema_embed_kernel(
    const float* __restrict__ esum, const float* __restrict__ embed_avg,
    const float* __restrict__ csnorm, float* __restrict__ out_w,
    float* __restrict__ out_ea) {
  __shared__ float tile[32][33];
  int kb = blockIdx.x & 31;   // 32 k-tiles
  int db = blockIdx.x >> 5;   // 16 d-tiles
  int tx = threadIdx.x & 31, ty = threadIdx.x >> 5;  // 32 x 8
#pragma unroll
  for (int i = 0; i < 4; ++i) {
    int kl = ty + i * 8;
    tile[kl][tx] = esum[(size_t)(kb * 32 + kl) * ND + db * 32 + tx];
  }
  __syncthreads();
#pragma unroll
  for (int i = 0; i < 4; ++i) {
    int d = db * 32 + ty + i * 8;
    int k = kb * 32 + tx;
    size_t idx = (size_t)d * NK + k;
    float nea = embed_avg[idx] * 0.99f + 0.01f * tile[tx][ty + i * 8];
    out_ea[idx] = nea;
    out_w[idx] = nea / csnorm[k];
  }
}

// ---------------- kernel 7: hist EMA ----------------
__global__ __launch_bounds__(256) void hist_kernel(const float* __restrict__ hist,
                                                   const float* __restrict__ bhist,
                                                   float* __restrict__ out_hist) {
  int i = blockIdx.x * 256 + threadIdx.x;
  out_hist[i] = hist[i] * 0.99f + 0.01f * bhist[i];
}

extern "C" void kernel_launch(void* const* d_in, const int* in_sizes, int n_in,
                              void* d_out, int out_size, void* d_ws, size_t ws_size,
                              hipStream_t stream) {
  const float* X = (const float*)d_in[0];
  const int* keys = (const int*)d_in[1];
  const float* W = (const float*)d_in[2];
  const float* cluster_size = (const float*)d_in[3];
  const float* embed_avg = (const float*)d_in[4];
  const float* hist = (const float*)d_in[5];

  float* wsf = (float*)d_ws;
  int* wsi = (int*)d_ws;
  int* counts = wsi + OFF_COUNTS;
  int* cursor = wsi + OFF_CURSOR;
  float* bhist = wsf + OFF_BHIST;
  float* wsq = wsf + OFF_WSQ;
  float* esum = wsf + OFF_ESUM;
  float* csnorm = wsf + OFF_CSNORM;
  int* offsets = wsi + OFF_OFFSETS;
  int* argmin_i = wsi + OFF_ARGMIN;
  int* order = wsi + OFF_ORDER;

  float* out = (float*)d_out;
  float* out_w = out;                               // [D*K]
  float* out_ncs = out + (size_t)ND * NK;           // [K]
  float* out_ea = out_ncs + NK;                     // [D*K]
  float* out_hist = out_ea + (size_t)ND * NK;       // [K*C]
  float* out_arg = out_hist + (size_t)NK * NC;      // [B]

  // zero counts/cursor/bhist/wsq/esum
  hipMemsetAsync(d_ws, 0, (size_t)OFF_ZERO_END * 4, stream);

  wsq_kernel<<<32, 256, 0, stream>>>(W, wsq);
  argmin_kernel<<<NB / 128, 256, 0, stream>>>(X, W, wsq, keys, argmin_i, out_arg,
                                              counts, bhist);
  scan_kernel<<<1, 1024, 0, stream>>>(counts, cluster_size, out_ncs, csnorm,
                                      offsets);
  reorder_kernel<<<NB / 256, 256, 0, stream>>>(argmin_i, offsets, cursor, order);
  gather_kernel<<<NK * NSPLIT, 256, 0, stream>>>(X, order, offsets, counts, esum);
  ema_embed_kernel<<<(NK / 32) * (ND / 32), 256, 0, stream>>>(esum, embed_avg,
                                                              csnorm, out_w, out_ea);
  hist_kernel<<<(NK * NC) / 256, 256, 0, stream>>>(hist, bhist, out_hist);
}

// Round 3
// 811.566 us; speedup vs baseline: 1.3694x; 1.3694x over previous
//
#include <hip/hip_runtime.h>

// clusteringEMA: B=65536, D=512, K=1024, C=100
// Distance GEMM as split-bf16 (hi trunc + lo RNE) x3 MFMA products, with
// second-best margin tracking + exact f32 rescore of ambiguous rows.

#define NB 65536
#define ND 512
#define NK 1024
#define NC 100
#define TAU 0.04f
#define FLAG_CAP 8192

typedef unsigned int u32;
typedef unsigned short u16;
typedef __attribute__((ext_vector_type(8))) short short8v;   // 8 bf16 in 4 VGPRs
typedef __attribute__((ext_vector_type(4))) float f32x4;

// ---------------- ws layout (float units) ----------------
#define OFF_COUNTS   0          // int [1024]
#define OFF_CURSOR   1024       // int [1024]
#define OFF_BHIST    2048       // float [102400]
#define OFF_WSQ      104448     // float [1024]
#define OFF_ESUM     105472     // float [1024*512]
#define OFF_FLAGCNT  629760     // int [64]
#define OFF_FLAGLIST 629824     // int [8192]
#define OFF_ZERO_END 638016
#define OFF_CSNORM   638016     // float [1024]
#define OFF_OFFSETS  639040     // int [1024]
#define OFF_ARGMIN   640064     // int [65536]
#define OFF_ORDER    705600     // int [65536]
#define OFF_WTHI     771136     // u16 [1024*512]  (262144 float slots)
#define OFF_WTLO     1033280    // u16 [1024*512]
#define OFF_WT32     1295424    // float [1024*512]

__device__ inline u32 pack_hi16(u32 u0, u32 u1) {
#if __has_builtin(__builtin_amdgcn_perm)
  return __builtin_amdgcn_perm(u1, u0, 0x07060302u);  // [u0.hi16 | u1.hi16<<16]
#else
  return (u0 >> 16) | (u1 & 0xffff0000u);
#endif
}

__device__ inline u32 rne_bits(float f) {   // bf16-RNE kept in bits[31:16]
  u32 u = __float_as_uint(f);
  return u + 0x7fffu + ((u >> 16) & 1u);
}

// 8 f32 -> hi plane (trunc-pack) + lo plane (RNE of exact residual)
__device__ inline void split8(const float4& a, const float4& b, uint4& hi, uint4& lo) {
  const float f[8] = {a.x, a.y, a.z, a.w, b.x, b.y, b.z, b.w};
  u32 h[4], l[4];
#pragma unroll
  for (int i = 0; i < 4; ++i) {
    u32 u0 = __float_as_uint(f[2 * i]);
    u32 u1 = __float_as_uint(f[2 * i + 1]);
    h[i] = pack_hi16(u0, u1);
    float l0 = f[2 * i] - __uint_as_float(u0 & 0xffff0000u);
    float l1 = f[2 * i + 1] - __uint_as_float(u1 & 0xffff0000u);
    l[i] = pack_hi16(rne_bits(l0), rne_bits(l1));
  }
  hi = make_uint4(h[0], h[1], h[2], h[3]);
  lo = make_uint4(l[0], l[1], l[2], l[3]);
}

__device__ inline f32x4 mfma16(short8v a, short8v b, f32x4 c) {
  return __builtin_amdgcn_mfma_f32_16x16x32_bf16(a, b, c, 0, 0, 0);
}

// ------ kernel 1: W -> Wt (transposed; split hi/lo bf16 + f32) + wsq ------
__global__ __launch_bounds__(256) void prep_w(const float* __restrict__ W,
                                              u16* __restrict__ Wthi,
                                              u16* __restrict__ Wtlo,
                                              float* __restrict__ Wt32,
                                              float* __restrict__ wsq) {
  __shared__ float tile[32][33];
  int db = blockIdx.x & 15;   // 16 d-tiles
  int kb = blockIdx.x >> 4;   // 32 k-tiles
  int tx = threadIdx.x & 31, ty = threadIdx.x >> 5;
  float s = 0.f;
#pragma unroll
  for (int i = 0; i < 4; ++i) {
    int d = db * 32 + ty + 8 * i;
    float wv = W[(size_t)d * NK + kb * 32 + tx];
    tile[ty + 8 * i][tx] = wv;
    s += wv * wv;
  }
  atomicAdd(&wsq[kb * 32 + tx], s);
  __syncthreads();
#pragma unroll
  for (int i = 0; i < 4; ++i) {
    int kl = ty + 8 * i;
    float f = tile[tx][kl];
    u32 u = __float_as_uint(f);
    size_t o = (size_t)(kb * 32 + kl) * ND + db * 32 + tx;
    Wt32[o] = f;
    Wthi[o] = (u16)(u >> 16);
    float lf = f - __uint_as_float(u & 0xffff0000u);
    Wtlo[o] = (u16)(rne_bits(lf) >> 16);
  }
}

// ---------------- kernel 2: MFMA distance-argmin with margin ----------------
__global__ __launch_bounds__(256, 2) void argmin_mfma(
    const float* __restrict__ X, const u16* __restrict__ Wthi,
    const u16* __restrict__ Wtlo, const float* __restrict__ wsq,
    int* __restrict__ argmin_i, float* __restrict__ argmin_f,
    int* __restrict__ flagCnt, int* __restrict__ flagList) {
  __shared__ __align__(16) u16 Ah[128 * 64];
  __shared__ __align__(16) u16 Al[128 * 64];
  __shared__ __align__(16) u16 Bh[128 * 64];
  __shared__ __align__(16) u16 Bl[128 * 64];
  __shared__ float wsq_s[NK];
  __shared__ float redV[128][2];
  __shared__ float redS[128][2];
  __shared__ int redI[128][2];

  const int t = threadIdx.x;
  const int lane = t & 63;
  const int w = t >> 6;
  const int g = lane >> 4;
  const int l15 = lane & 15;
  const int wrb = (w >> 1) * 64;  // wave row base
  const int wcb = (w & 1) * 64;   // wave col base
  const int brow = blockIdx.x * 128;

#pragma unroll
  for (int i = 0; i < 4; ++i) wsq_s[t + 256 * i] = wsq[t + 256 * i];

  // staging map: thread -> (rows sr+32q, 16B chunk sc8), XOR-swizzled LDS slot
  const int sr = t >> 3;
  const int sc8 = t & 7;
  const u32 lds_base = sr * 64 + (u32)((sc8 ^ (sr & 7)) * 8);
  const float* Abase = X + (size_t)(brow + sr) * ND + sc8 * 8;
  const size_t brow_off = (size_t)sr * ND + sc8 * 8;

  // fragment LDS offsets (u16 units), per kk half of BK=64
  int aofs[2], bofs[2];
#pragma unroll
  for (int kk = 0; kk < 2; ++kk) {
    aofs[kk] = (wrb + l15) * 64 + (((kk * 4 + g) ^ (l15 & 7)) * 8);
    bofs[kk] = (wcb + l15) * 64 + (((kk * 4 + g) ^ (l15 & 7)) * 8);
  }

  float bestV[4][4], secV[4][4];
  int bestI[4][4];
#pragma unroll
  for (int m = 0; m < 4; ++m)
#pragma unroll
    for (int r = 0; r < 4; ++r) {
      bestV[m][r] = 3.4e38f; secV[m][r] = 3.4e38f; bestI[m][r] = 0;
    }

  float4 ar[8];
  uint4 br[8];

  for (int ct = 0; ct < 8; ++ct) {
    f32x4 acc[4][4];
#pragma unroll
    for (int m = 0; m < 4; ++m)
#pragma unroll
      for (int n = 0; n < 4; ++n) acc[m][n] = (f32x4)0.f;

    const u16* Bh_g = Wthi + (size_t)(ct * 128) * ND + brow_off;
    const u16* Bl_g = Wtlo + (size_t)(ct * 128) * ND + brow_off;

    // prefetch k-chunk 0
#pragma unroll
    for (int q = 0; q < 4; ++q) {
      ar[2 * q] = *(const float4*)(Abase + q * 32 * ND);
      ar[2 * q + 1] = *(const float4*)(Abase + q * 32 * ND + 4);
      br[q] = *(const uint4*)(Bh_g + q * 32 * ND);
      br[4 + q] = *(const uint4*)(Bl_g + q * 32 * ND);
    }

    for (int kc = 0; kc < 8; ++kc) {
      __syncthreads();   // previous compute done reading LDS
#pragma unroll
      for (int q = 0; q < 4; ++q) {
        uint4 hi, lo;
        split8(ar[2 * q], ar[2 * q + 1], hi, lo);
        *(uint4*)&Ah[lds_base + q * 2048] = hi;
        *(uint4*)&Al[lds_base + q * 2048] = lo;
        *(uint4*)&Bh[lds_base + q * 2048] = br[q];
        *(uint4*)&Bl[lds_base + q * 2048] = br[4 + q];
      }
      __syncthreads();
      if (kc < 7) {   // prefetch next chunk; hides under the MFMA below
        const float* ap = Abase + (kc + 1) * 64;
        const u16* bp = Bh_g + (kc + 1) * 64;
        const u16* bp2 = Bl_g + (kc + 1) * 64;
#pragma unroll
        for (int q = 0; q < 4; ++q) {
          ar[2 * q] = *(const float4*)(ap + q * 32 * ND);
          ar[2 * q + 1] = *(const float4*)(ap + q * 32 * ND + 4);
          br[q] = *(const uint4*)(bp + q * 32 * ND);
          br[4 + q] = *(const uint4*)(bp2 + q * 32 * ND);
        }
      }
#pragma unroll
      for (int kk = 0; kk < 2; ++kk) {
        short8v a_h[4], a_l[4];
#pragma unroll
        for (int m = 0; m < 4; ++m) {
          a_h[m] = *(const short8v*)&Ah[aofs[kk] + m * 1024];
          a_l[m] = *(const short8v*)&Al[aofs[kk] + m * 1024];
        }
#pragma unroll
        for (int n = 0; n < 4; ++n) {
          short8v b_h = *(const short8v*)&Bh[bofs[kk] + n * 1024];
          short8v b_l = *(const short8v*)&Bl[bofs[kk] + n * 1024];
#pragma unroll
          for (int m = 0; m < 4; ++m) {
            acc[m][n] = mfma16(a_h[m], b_h, acc[m][n]);
            acc[m][n] = mfma16(a_h[m], b_l, acc[m][n]);
            acc[m][n] = mfma16(a_l[m], b_h, acc[m][n]);
          }
        }
      }
    }

    // epilogue: running (best, second) argmin.
    // C layout: col = 16n + (lane&15), row = 16m + 4*(lane>>4) + r
#pragma unroll
    for (int n = 0; n < 4; ++n) {
      int col = ct * 128 + wcb + 16 * n + l15;
      float wq = wsq_s[col];
#pragma unroll
      for (int m = 0; m < 4; ++m)
#pragma unroll
        for (int r = 0; r < 4; ++r) {
          float v = wq - 2.0f * acc[m][n][r];
          if (v < bestV[m][r]) {
            secV[m][r] = bestV[m][r];
            bestV[m][r] = v;
            bestI[m][r] = col;
          } else if (v < secV[m][r]) {
            secV[m][r] = v;
          }
        }
    }
  }

  // cross-lane reduce: 16 lanes share each row; merge (b1,idx,b2) triples
#pragma unroll
  for (int m = 0; m < 4; ++m)
#pragma unroll
    for (int r = 0; r < 4; ++r) {
      float v = bestV[m][r];
      float sec = secV[m][r];
      int idx = bestI[m][r];
#pragma unroll
      for (int mask = 1; mask < 16; mask <<= 1) {
        float ov = __shfl_xor(v, mask, 64);
        float os = __shfl_xor(sec, mask, 64);
        int oi = __shfl_xor(idx, mask, 64);
        float nsec = fminf(fminf(sec, os), fmaxf(v, ov));
        if (ov < v || (ov == v && oi < idx)) { v = ov; idx = oi; }
        sec = nsec;
      }
      if (l15 == 0) {
        int rowl = wrb + 16 * m + 4 * g + r;
        redV[rowl][w & 1] = v;
        redS[rowl][w & 1] = sec;
        redI[rowl][w & 1] = idx;
      }
    }
  __syncthreads();
  if (t < 128) {
    float v0 = redV[t][0], v1 = redV[t][1];
    float s0 = redS[t][0], s1 = redS[t][1];
    int i0 = redI[t][0], i1 = redI[t][1];
    float bv, sec;
    int bi;
    if (v1 < v0 || (v1 == v0 && i1 < i0)) { bv = v1; bi = i1; }
    else { bv = v0; bi = i0; }
    sec = fminf(fminf(s0, s1), fmaxf(v0, v1));
    int b = brow + t;
    argmin_i[b] = bi;
    argmin_f[b] = (float)bi;
    if (sec - bv < TAU) {   // ambiguous: schedule exact rescore
      int slot = atomicAdd(flagCnt, 1);
      if (slot < FLAG_CAP) flagList[slot] = b;
    }
  }
}

// ---------------- kernel 3: exact f32 rescore of flagged rows ----------------
__global__ __launch_bounds__(256) void fixup_kernel(
    const float* __restrict__ X, const float* __restrict__ Wt32,
    const float* __restrict__ wsq, const int* __restrict__ flagCnt,
    const int* __restrict__ flagList, int* __restrict__ argmin_i,
    float* __restrict__ argmin_f) {
  __shared__ float xs[ND];
  __shared__ float rv[256];
  __shared__ int ri[256];
  int n = *flagCnt;
  if (n > FLAG_CAP) n = FLAG_CAP;
  int t = threadIdx.x;
  for (int i = blockIdx.x; i < n; i += gridDim.x) {
    int row = flagList[i];
    if (t < 128) ((float4*)xs)[t] = ((const float4*)(X + (size_t)row * ND))[t];
    __syncthreads();
    float bv = 3.4e38f;
    int bi = 0;
#pragma unroll
    for (int kk = 0; kk < 4; ++kk) {
      int k = t + 256 * kk;   // ascending per thread -> strict < keeps first
      const float* wrow = Wt32 + (size_t)k * ND;
      float p0 = 0.f, p1 = 0.f, p2 = 0.f, p3 = 0.f;
      for (int d = 0; d < ND; d += 4) {
        float4 wv = *(const float4*)(wrow + d);
        float4 xv = *(const float4*)(xs + d);
        p0 += xv.x * wv.x; p1 += xv.y * wv.y;
        p2 += xv.z * wv.z; p3 += xv.w * wv.w;
      }
      float v = wsq[k] - 2.0f * ((p0 + p1) + (p2 + p3));
      if (v < bv) { bv = v; bi = k; }
    }
    rv[t] = bv; ri[t] = bi;
    __syncthreads();
    for (int s = 128; s > 0; s >>= 1) {
      if (t < s) {
        float ov = rv[t + s]; int oi = ri[t + s];
        if (ov < rv[t] || (ov == rv[t] && oi < ri[t])) { rv[t] = ov; ri[t] = oi; }
      }
      __syncthreads();
    }
    if (t == 0) { argmin_i[row] = ri[0]; argmin_f[row] = (float)ri[0]; }
    __syncthreads();   // xs reused next iteration
  }
}

// ---------------- kernel 4: counts + class histogram ----------------
__global__ __launch_bounds__(256) void stats_kernel(
    const int* __restrict__ argmin_i, const int* __restrict__ keys,
    int* __restrict__ counts, float* __restrict__ bhist) {
  int b = blockIdx.x * 256 + threadIdx.x;
  int k = argmin_i[b];
  atomicAdd(&counts[k], 1);
  atomicAdd(&bhist[(size_t)k * NC + keys[b]], 1.0f);
}

// ---------------- kernel 5: scan + cluster_size EMA + cs_norm ----------------
__global__ __launch_bounds__(1024) void scan_kernel(
    const int* __restrict__ counts, const float* __restrict__ cluster_size,
    float* __restrict__ out_ncs, float* __restrict__ csnorm,
    int* __restrict__ offsets) {
  __shared__ float sf[1024];
  __shared__ int si[1024];
  int t = threadIdx.x;
  int cnt = counts[t];
  float ncs = cluster_size[t] * 0.99f + 0.01f * (cnt == 0 ? 1.0f : (float)cnt);
  out_ncs[t] = ncs;

  sf[t] = ncs;
  __syncthreads();
  for (int s = 512; s > 0; s >>= 1) {
    if (t < s) sf[t] += sf[t + s];
    __syncthreads();
  }
  float n = sf[0];
  csnorm[t] = (ncs + 1e-5f) / (n + 1024.0f * 1e-5f) * n;

  si[t] = cnt;
  __syncthreads();
  for (int s = 1; s < 1024; s <<= 1) {
    int v = (t >= s) ? si[t - s] : 0;
    __syncthreads();
    si[t] += v;
    __syncthreads();
  }
  offsets[t] = si[t] - cnt;
}

// ---------------- kernel 6: reorder rows by cluster ----------------
__global__ __launch_bounds__(256) void reorder_kernel(
    const int* __restrict__ argmin_i, const int* __restrict__ offsets,
    int* __restrict__ cursor, int* __restrict__ order) {
  int b = blockIdx.x * 256 + threadIdx.x;
  int k = argmin_i[b];
  int pos = atomicAdd(&cursor[k], 1);
  order[offsets[k] + pos] = b;
}

// ---------------- kernel 7: split gather-sum into esum[K][D] ----------------
#define NSPLIT 8
__global__ __launch_bounds__(256) void gather_kernel(
    const float* __restrict__ X, const int* __restrict__ order,
    const int* __restrict__ offsets, const int* __restrict__ counts,
    float* __restrict__ esum) {
  int k = blockIdx.x >> 3;
  int s = blockIdx.x & 7;
  int cnt = counts[k], start = offsets[k];
  int t = threadIdx.x;
  float a0 = 0.f, a1 = 0.f;
  for (int m = s; m < cnt; m += NSPLIT) {
    int b = order[start + m];
    const float* row = X + (size_t)b * ND;
    a0 += row[t];
    a1 += row[t + 256];
  }
  if (s < cnt) {
    atomicAdd(&esum[(size_t)k * ND + t], a0);
    atomicAdd(&esum[(size_t)k * ND + t + 256], a1);
  }
}

// ---------------- kernel 8: embed_avg EMA + weight (with transpose) ----------
__global__ __launch_bounds__(256) void ema_embed_kernel(
    const float* __restrict__ esum, const float* __restrict__ embed_avg,
    const float* __restrict__ csnorm, float* __restrict__ out_w,
    float* __restrict__ out_ea) {
  __shared__ float tile[32][33];
  int kb = blockIdx.x & 31;
  int db = blockIdx.x >> 5;
  int tx = threadIdx.x & 31, ty = threadIdx.x >> 5;
#pragma unroll
  for (int i = 0; i < 4; ++i) {
    int kl = ty + i * 8;
    tile[kl][tx] = esum[(size_t)(kb * 32 + kl) * ND + db * 32 + tx];
  }
  __syncthreads();
#pragma unroll
  for (int i = 0; i < 4; ++i) {
    int d = db * 32 + ty + i * 8;
    int k = kb * 32 + tx;
    size_t idx = (size_t)d * NK + k;
    float nea = embed_avg[idx] * 0.99f + 0.01f * tile[tx][ty + i * 8];
    out_ea[idx] = nea;
    out_w[idx] = nea / csnorm[k];
  }
}

// ---------------- kernel 9: hist EMA ----------------
__global__ __launch_bounds__(256) void hist_kernel(const float* __restrict__ hist,
                                                   const float* __restrict__ bhist,
                                                   float* __restrict__ out_hist) {
  int i = blockIdx.x * 256 + threadIdx.x;
  out_hist[i] = hist[i] * 0.99f + 0.01f * bhist[i];
}

extern "C" void kernel_launch(void* const* d_in, const int* in_sizes, int n_in,
                              void* d_out, int out_size, void* d_ws, size_t ws_size,
                              hipStream_t stream) {
  const float* X = (const float*)d_in[0];
  const int* keys = (const int*)d_in[1];
  const float* W = (const float*)d_in[2];
  const float* cluster_size = (const float*)d_in[3];
  const float* embed_avg = (const float*)d_in[4];
  const float* hist = (const float*)d_in[5];

  float* wsf = (float*)d_ws;
  int* wsi = (int*)d_ws;
  int* counts = wsi + OFF_COUNTS;
  int* cursor = wsi + OFF_CURSOR;
  float* bhist = wsf + OFF_BHIST;
  float* wsq = wsf + OFF_WSQ;
  float* esum = wsf + OFF_ESUM;
  int* flagCnt = wsi + OFF_FLAGCNT;
  int* flagList = wsi + OFF_FLAGLIST;
  float* csnorm = wsf + OFF_CSNORM;
  int* offsets = wsi + OFF_OFFSETS;
  int* argmin_i = wsi + OFF_ARGMIN;
  int* order = wsi + OFF_ORDER;
  u16* Wthi = (u16*)(wsf + OFF_WTHI);
  u16* Wtlo = (u16*)(wsf + OFF_WTLO);
  float* Wt32 = wsf + OFF_WT32;

  float* out = (float*)d_out;
  float* out_w = out;
  float* out_ncs = out + (size_t)ND * NK;
  float* out_ea = out_ncs + NK;
  float* out_hist = out_ea + (size_t)ND * NK;
  float* out_arg = out_hist + (size_t)NK * NC;

  hipMemsetAsync(d_ws, 0, (size_t)OFF_ZERO_END * 4, stream);

  prep_w<<<512, 256, 0, stream>>>(W, Wthi, Wtlo, Wt32, wsq);
  argmin_mfma<<<NB / 128, 256, 0, stream>>>(X, Wthi, Wtlo, wsq, argmin_i,
                                            out_arg, flagCnt, flagList);
  fixup_kernel<<<128, 256, 0, stream>>>(X, Wt32, wsq, flagCnt, flagList,
                                        argmin_i, out_arg);
  stats_kernel<<<NB / 256, 256, 0, stream>>>(argmin_i, keys, counts, bhist);
  scan_kernel<<<1, 1024, 0, stream>>>(counts, cluster_size, out_ncs, csnorm,
                                      offsets);
  reorder_kernel<<<NB / 256, 256, 0, stream>>>(argmin_i, offsets, cursor, order);
  gather_kernel<<<NK * NSPLIT, 256, 0, stream>>>(X, order, offsets, counts, esum);
  ema_embed_kernel<<<(NK / 32) * (ND / 32), 256, 0, stream>>>(esum, embed_avg,
                                                              csnorm, out_w, out_ea);
  hist_kernel<<<(NK * NC) / 256, 256, 0, stream>>>(hist, bhist, out_hist);
}

// Round 4
// 570.954 us; speedup vs baseline: 1.9464x; 1.4214x over previous
//
#include <hip/hip_runtime.h>

// clusteringEMA: B=65536, D=512, K=1024, C=100
// Distance GEMM: split-bf16 (hi trunc + lo RNE) x3 MFMA, B staged via
// global_load_lds (no regs), A reg-staged+split. Margin-tracked argmin with
// exact f32 rescore of ambiguous rows.

#define NB 65536
#define ND 512
#define NK 1024
#define NC 100
#define TAU 0.04f
#define FLAG_CAP 8192

typedef unsigned int u32;
typedef unsigned short u16;
typedef __attribute__((ext_vector_type(8))) short short8v;   // 8 bf16 in 4 VGPRs
typedef __attribute__((ext_vector_type(4))) float f32x4;

// ---------------- ws layout (4-byte units) ----------------
#define OFF_COUNTS   0          // int [1024]
#define OFF_CURSOR   1024       // int [1024]
#define OFF_BHIST    2048       // float [102400]
#define OFF_FLAGCNT  104448     // int [64]
#define OFF_WSQ      104512     // float [1024]
#define OFF_ZERO_END 105536
#define OFF_FLAGLIST 105536     // int [8192]
#define OFF_CSNORM   113728     // float [1024]
#define OFF_OFFSETS  114752     // int [1024]
#define OFF_ARGMIN   115776     // int [65536]
#define OFF_ORDER    181312     // int [65536]
#define OFF_WTHI     246848     // u16 [1024*512]
#define OFF_WTLO     508992     // u16 [1024*512]
#define OFF_WT32     771136     // float [1024*512]
#define OFF_ESUM     1295424    // path B: float [1024*512]; path A: float [8][1024][512]
#define WS_NEED_A  (((size_t)OFF_ESUM + (size_t)8 * NK * ND) * 4)
#define WS_NEED_B  (((size_t)OFF_ESUM + (size_t)NK * ND) * 4)

__device__ inline u32 pack_hi16(u32 u0, u32 u1) {
#if __has_builtin(__builtin_amdgcn_perm)
  return __builtin_amdgcn_perm(u1, u0, 0x07060302u);  // [u0.hi16 | u1.hi16<<16]
#else
  return (u0 >> 16) | (u1 & 0xffff0000u);
#endif
}

__device__ inline u32 rne_bits(float f) {   // bf16-RNE kept in bits[31:16]
  u32 u = __float_as_uint(f);
  return u + 0x7fffu + ((u >> 16) & 1u);
}

// 8 f32 -> hi plane (trunc-pack) + lo plane (RNE of exact residual)
__device__ inline void split8(const float4& a, const float4& b, uint4& hi, uint4& lo) {
  const float f[8] = {a.x, a.y, a.z, a.w, b.x, b.y, b.z, b.w};
  u32 h[4], l[4];
#pragma unroll
  for (int i = 0; i < 4; ++i) {
    u32 u0 = __float_as_uint(f[2 * i]);
    u32 u1 = __float_as_uint(f[2 * i + 1]);
    h[i] = pack_hi16(u0, u1);
    float l0 = f[2 * i] - __uint_as_float(u0 & 0xffff0000u);
    float l1 = f[2 * i + 1] - __uint_as_float(u1 & 0xffff0000u);
    l[i] = pack_hi16(rne_bits(l0), rne_bits(l1));
  }
  hi = make_uint4(h[0], h[1], h[2], h[3]);
  lo = make_uint4(l[0], l[1], l[2], l[3]);
}

__device__ inline f32x4 mfma16(short8v a, short8v b, f32x4 c) {
  return __builtin_amdgcn_mfma_f32_16x16x32_bf16(a, b, c, 0, 0, 0);
}

// async 16B global -> LDS (linear dest: base + lane*16)
__device__ __forceinline__ void gl_lds16(const u16* g, u16* l) {
  __builtin_amdgcn_global_load_lds(
      (const __attribute__((address_space(1))) u32*)g,
      (__attribute__((address_space(3))) u32*)l, 16, 0, 0);
}

// ------ kernel 1: W -> Wt (transposed; split hi/lo bf16 + f32) + wsq ------
__global__ __launch_bounds__(256) void prep_w(const float* __restrict__ W,
                                              u16* __restrict__ Wthi,
                                              u16* __restrict__ Wtlo,
                                              float* __restrict__ Wt32,
                                              float* __restrict__ wsq) {
  __shared__ float tile[32][33];
  int db = blockIdx.x & 15;   // 16 d-tiles
  int kb = blockIdx.x >> 4;   // 32 k-tiles
  int tx = threadIdx.x & 31, ty = threadIdx.x >> 5;
  float s = 0.f;
#pragma unroll
  for (int i = 0; i < 4; ++i) {
    int d = db * 32 + ty + 8 * i;
    float wv = W[(size_t)d * NK + kb * 32 + tx];
    tile[ty + 8 * i][tx] = wv;
    s += wv * wv;
  }
  atomicAdd(&wsq[kb * 32 + tx], s);
  __syncthreads();
#pragma unroll
  for (int i = 0; i < 4; ++i) {
    int kl = ty + 8 * i;
    float f = tile[tx][kl];
    u32 u = __float_as_uint(f);
    size_t o = (size_t)(kb * 32 + kl) * ND + db * 32 + tx;
    Wt32[o] = f;
    Wthi[o] = (u16)(u >> 16);
    float lf = f - __uint_as_float(u & 0xffff0000u);
    Wtlo[o] = (u16)(rne_bits(lf) >> 16);
  }
}

// ---------------- kernel 2: MFMA distance-argmin with margin ----------------
__global__ __launch_bounds__(256, 2) void argmin_mfma(
    const float* __restrict__ X, const u16* __restrict__ Wthi,
    const u16* __restrict__ Wtlo, const float* __restrict__ wsq,
    const int* __restrict__ keys,
    int* __restrict__ argmin_i, float* __restrict__ argmin_f,
    int* __restrict__ counts, float* __restrict__ bhist,
    int* __restrict__ flagCnt, int* __restrict__ flagList) {
  __shared__ __align__(16) u16 Ah[128 * 64];
  __shared__ __align__(16) u16 Al[128 * 64];
  __shared__ __align__(16) u16 Bh[128 * 64];
  __shared__ __align__(16) u16 Bl[128 * 64];
  __shared__ float wsq_s[NK];
  __shared__ float redV[128][2];
  __shared__ float redS[128][2];
  __shared__ int redI[128][2];

  const int t = threadIdx.x;
  const int lane = t & 63;
  const int w = t >> 6;
  const int g = lane >> 4;
  const int l15 = lane & 15;
  const int wrb = (w >> 1) * 64;  // wave row base
  const int wcb = (w & 1) * 64;   // wave col base
  const int brow = blockIdx.x * 128;

#pragma unroll
  for (int i = 0; i < 4; ++i) wsq_s[t + 256 * i] = wsq[t + 256 * i];

  // A staging (reg load -> split -> ds_write): thread covers rows (t>>3)+32q,
  // chunk t&7; phys chunk XOR-swizzled by row&7
  const int asr = t >> 3;
  const int ac8 = t & 7;
  const u32 a_lds = asr * 64 + (u32)((ac8 ^ (asr & 7)) * 8);   // u16 units
  const float* Abase = X + (size_t)(brow + asr) * ND + ac8 * 8;

  // B staging via global_load_lds: linear LDS dest, swizzle folded into the
  // per-lane global source (involution: phys c8p holds source chunk c8p^sub)
  const int sub = lane >> 3;   // row-in-8 covered by this lane
  const int c8p = lane & 7;    // phys chunk written by this lane
  const size_t bsrc = (size_t)(w * 32 + sub) * ND + (size_t)((c8p ^ sub) * 8);

  // fragment LDS read offsets (u16 units), per kk half of BK=64
  int aofs[2], bofs[2];
#pragma unroll
  for (int kk = 0; kk < 2; ++kk) {
    aofs[kk] = (wrb + l15) * 64 + (((kk * 4 + g) ^ (l15 & 7)) * 8);
    bofs[kk] = (wcb + l15) * 64 + (((kk * 4 + g) ^ (l15 & 7)) * 8);
  }

  float bestV[4][4], secV[4][4];
  int bestI[4][4];
#pragma unroll
  for (int m = 0; m < 4; ++m)
#pragma unroll
    for (int r = 0; r < 4; ++r) {
      bestV[m][r] = 3.4e38f; secV[m][r] = 3.4e38f; bestI[m][r] = 0;
    }

  float4 ar[8];

  for (int ct = 0; ct < 8; ++ct) {
    f32x4 acc[4][4];
#pragma unroll
    for (int m = 0; m < 4; ++m)
#pragma unroll
      for (int n = 0; n < 4; ++n) acc[m][n] = (f32x4)0.f;

    const u16* BhT = Wthi + (size_t)(ct * 128) * ND + bsrc;
    const u16* BlT = Wtlo + (size_t)(ct * 128) * ND + bsrc;

    // prologue: A regs for k-chunk 0
#pragma unroll
    for (int q = 0; q < 4; ++q) {
      ar[2 * q] = *(const float4*)(Abase + q * 32 * ND);
      ar[2 * q + 1] = *(const float4*)(Abase + q * 32 * ND + 4);
    }

    for (int kc = 0; kc < 8; ++kc) {
      __syncthreads();   // previous chunk's MFMA reads done
      // B planes: async copies, 4 waves x 4 issues x 2 planes cover 128 rows
#pragma unroll
      for (int q = 0; q < 4; ++q) {
        gl_lds16(BhT + kc * 64 + (size_t)(q * 8) * ND, &Bh[(w * 32 + q * 8) * 64]);
        gl_lds16(BlT + kc * 64 + (size_t)(q * 8) * ND, &Bl[(w * 32 + q * 8) * 64]);
      }
      // A: split in-flight regs, write swizzled
#pragma unroll
      for (int q = 0; q < 4; ++q) {
        uint4 hi, lo;
        split8(ar[2 * q], ar[2 * q + 1], hi, lo);
        *(uint4*)&Ah[a_lds + q * 2048] = hi;
        *(uint4*)&Al[a_lds + q * 2048] = lo;
      }
      __syncthreads();   // drains vmcnt (async copies) + lgkmcnt (ds_write)
      if (kc < 7) {      // prefetch next A chunk; hides under MFMA
        const float* ap = Abase + (kc + 1) * 64;
#pragma unroll
        for (int q = 0; q < 4; ++q) {
          ar[2 * q] = *(const float4*)(ap + q * 32 * ND);
          ar[2 * q + 1] = *(const float4*)(ap + q * 32 * ND + 4);
        }
      }
#pragma unroll
      for (int kk = 0; kk < 2; ++kk) {
        short8v a_h[4], a_l[4];
#pragma unroll
        for (int m = 0; m < 4; ++m) {
          a_h[m] = *(const short8v*)&Ah[aofs[kk] + m * 1024];
          a_l[m] = *(const short8v*)&Al[aofs[kk] + m * 1024];
        }
#pragma unroll
        for (int n = 0; n < 4; ++n) {
          short8v b_h = *(const short8v*)&Bh[bofs[kk] + n * 1024];
          short8v b_l = *(const short8v*)&Bl[bofs[kk] + n * 1024];
#pragma unroll
          for (int m = 0; m < 4; ++m) {
            acc[m][n] = mfma16(a_h[m], b_h, acc[m][n]);
            acc[m][n] = mfma16(a_h[m], b_l, acc[m][n]);
            acc[m][n] = mfma16(a_l[m], b_h, acc[m][n]);
          }
        }
      }
    }

    // epilogue: running (best, second). C layout: col=16n+(lane&15),
    // row = 16m + 4*(lane>>4) + r
#pragma unroll
    for (int n = 0; n < 4; ++n) {
      int col = ct * 128 + wcb + 16 * n + l15;
      float wq = wsq_s[col];
#pragma unroll
      for (int m = 0; m < 4; ++m)
#pragma unroll
        for (int r = 0; r < 4; ++r) {
          float v = wq - 2.0f * acc[m][n][r];
          if (v < bestV[m][r]) {
            secV[m][r] = bestV[m][r];
            bestV[m][r] = v;
            bestI[m][r] = col;
          } else if (v < secV[m][r]) {
            secV[m][r] = v;
          }
        }
    }
  }

  // cross-lane reduce: 16 lanes share each row; merge (b1,idx,b2)
#pragma unroll
  for (int m = 0; m < 4; ++m)
#pragma unroll
    for (int r = 0; r < 4; ++r) {
      float v = bestV[m][r];
      float sec = secV[m][r];
      int idx = bestI[m][r];
#pragma unroll
      for (int mask = 1; mask < 16; mask <<= 1) {
        float ov = __shfl_xor(v, mask, 64);
        float os = __shfl_xor(sec, mask, 64);
        int oi = __shfl_xor(idx, mask, 64);
        float nsec = fminf(fminf(sec, os), fmaxf(v, ov));
        if (ov < v || (ov == v && oi < idx)) { v = ov; idx = oi; }
        sec = nsec;
      }
      if (l15 == 0) {
        int rowl = wrb + 16 * m + 4 * g + r;
        redV[rowl][w & 1] = v;
        redS[rowl][w & 1] = sec;
        redI[rowl][w & 1] = idx;
      }
    }
  __syncthreads();
  if (t < 128) {
    float v0 = redV[t][0], v1 = redV[t][1];
    float s0 = redS[t][0], s1 = redS[t][1];
    int i0 = redI[t][0], i1 = redI[t][1];
    float bv, sec;
    int bi;
    if (v1 < v0 || (v1 == v0 && i1 < i0)) { bv = v1; bi = i1; }
    else { bv = v0; bi = i0; }
    sec = fminf(fminf(s0, s1), fmaxf(v0, v1));
    int b = brow + t;
    argmin_i[b] = bi;
    argmin_f[b] = (float)bi;
    atomicAdd(&counts[bi], 1);
    atomicAdd(&bhist[(size_t)bi * NC + keys[b]], 1.0f);
    if (sec - bv < TAU) {   // ambiguous: exact rescore later
      int slot = atomicAdd(flagCnt, 1);
      if (slot < FLAG_CAP) flagList[slot] = b;
    }
  }
}

// ---- kernel 3: exact f32 rescore of flagged rows (+ count/hist adjust) ----
__global__ __launch_bounds__(256) void fixup_kernel(
    const float* __restrict__ X, const float* __restrict__ Wt32,
    const float* __restrict__ wsq, const int* __restrict__ keys,
    const int* __restrict__ flagCnt, const int* __restrict__ flagList,
    int* __restrict__ argmin_i, float* __restrict__ argmin_f,
    int* __restrict__ counts, float* __restrict__ bhist) {
  __shared__ float xs[ND];
  __shared__ float rv[256];
  __shared__ int ri[256];
  int n = *flagCnt;
  if (n > FLAG_CAP) n = FLAG_CAP;
  int t = threadIdx.x;
  for (int i = blockIdx.x; i < n; i += gridDim.x) {
    int row = flagList[i];
    if (t < 128) ((float4*)xs)[t] = ((const float4*)(X + (size_t)row * ND))[t];
    __syncthreads();
    float bv = 3.4e38f;
    int bi = 0;
#pragma unroll
    for (int kk = 0; kk < 4; ++kk) {
      int k = t + 256 * kk;   // ascending per thread -> strict < keeps first
      const float* wrow = Wt32 + (size_t)k * ND;
      float p0 = 0.f, p1 = 0.f, p2 = 0.f, p3 = 0.f;
      for (int d = 0; d < ND; d += 4) {
        float4 wv = *(const float4*)(wrow + d);
        float4 xv = *(const float4*)(xs + d);
        p0 += xv.x * wv.x; p1 += xv.y * wv.y;
        p2 += xv.z * wv.z; p3 += xv.w * wv.w;
      }
      float v = wsq[k] - 2.0f * ((p0 + p1) + (p2 + p3));
      if (v < bv) { bv = v; bi = k; }
    }
    rv[t] = bv; ri[t] = bi;
    __syncthreads();
    for (int s = 128; s > 0; s >>= 1) {
      if (t < s) {
        float ov = rv[t + s]; int oi = ri[t + s];
        if (ov < rv[t] || (ov == rv[t] && oi < ri[t])) { rv[t] = ov; ri[t] = oi; }
      }
      __syncthreads();
    }
    if (t == 0) {
      int nw = ri[0];
      int old = argmin_i[row];
      if (nw != old) {
        argmin_i[row] = nw;
        argmin_f[row] = (float)nw;
        atomicSub(&counts[old], 1);
        atomicAdd(&counts[nw], 1);
        int c = keys[row];
        atomicAdd(&bhist[(size_t)old * NC + c], -1.0f);
        atomicAdd(&bhist[(size_t)nw * NC + c], 1.0f);
      }
    }
    __syncthreads();   // xs reused next iteration
  }
}

// -------- kernel 4: scan + cluster_size EMA + cs_norm (wave shuffles) -------
__global__ __launch_bounds__(1024) void scan_kernel(
    const int* __restrict__ counts, const float* __restrict__ cluster_size,
    float* __restrict__ out_ncs, float* __restrict__ csnorm,
    int* __restrict__ offsets) {
  __shared__ float wsum[16];
  __shared__ int wcnt[16];
  int t = threadIdx.x, lane = t & 63, wv = t >> 6;
  int cnt = counts[t];
  float ncs = cluster_size[t] * 0.99f + 0.01f * (cnt == 0 ? 1.0f : (float)cnt);
  out_ncs[t] = ncs;

  float s = ncs;
#pragma unroll
  for (int m = 1; m < 64; m <<= 1) s += __shfl_xor(s, m, 64);
  int ic = cnt;   // inclusive scan within wave
#pragma unroll
  for (int o = 1; o < 64; o <<= 1) {
    int v = __shfl_up(ic, o, 64);
    if (lane >= o) ic += v;
  }
  if (lane == 63) { wsum[wv] = s; wcnt[wv] = ic; }
  __syncthreads();
  float n = 0.f;
  int coff = 0;
  for (int i = 0; i < 16; ++i) {
    n += wsum[i];
    if (i < wv) coff += wcnt[i];
  }
  csnorm[t] = (ncs + 1e-5f) / (n + 1024.0f * 1e-5f) * n;
  offsets[t] = coff + ic - cnt;   // exclusive prefix
}

// ---------------- kernel 5: reorder rows by cluster ----------------
__global__ __launch_bounds__(256) void reorder_kernel(
    const int* __restrict__ argmin_i, const int* __restrict__ offsets,
    int* __restrict__ cursor, int* __restrict__ order) {
  int b = blockIdx.x * 256 + threadIdx.x;
  int k = argmin_i[b];
  int pos = atomicAdd(&cursor[k], 1);
  order[offsets[k] + pos] = b;
}

// -------- kernel 6a: split gather-sum, atomic-free, 8 planes (path A) -------
__global__ __launch_bounds__(256) void gather_planes(
    const float* __restrict__ X, const int* __restrict__ order,
    const int* __restrict__ offsets, const int* __restrict__ counts,
    float* __restrict__ esumP) {
  int k = blockIdx.x >> 3;
  int s = blockIdx.x & 7;
  int cnt = counts[k], start = offsets[k];
  int t = threadIdx.x;
  float a0 = 0.f, a1 = 0.f;
  for (int m = s; m < cnt; m += 8) {
    int b = order[start + m];
    const float* row = X + (size_t)b * ND;
    a0 += row[t];
    a1 += row[t + 256];
  }
  size_t o = ((size_t)s * NK + k) * ND + t;   // always store (covers cnt==0)
  esumP[o] = a0;
  esumP[o + 256] = a1;
}

// -------- kernel 6b: split gather-sum with atomics (path B fallback) --------
__global__ __launch_bounds__(256) void gather_atomic(
    const float* __restrict__ X, const int* __restrict__ order,
    const int* __restrict__ offsets, const int* __restrict__ counts,
    float* __restrict__ esum) {
  int k = blockIdx.x >> 3;
  int s = blockIdx.x & 7;
  int cnt = counts[k], start = offsets[k];
  int t = threadIdx.x;
  float a0 = 0.f, a1 = 0.f;
  for (int m = s; m < cnt; m += 8) {
    int b = order[start + m];
    const float* row = X + (size_t)b * ND;
    a0 += row[t];
    a1 += row[t + 256];
  }
  if (s < cnt) {
    atomicAdd(&esum[(size_t)k * ND + t], a0);
    atomicAdd(&esum[(size_t)k * ND + t + 256], a1);
  }
}

// ------- kernel 7: embed_avg EMA + weight (transpose; sums nplanes) --------
__global__ __launch_bounds__(256) void ema_embed_kernel(
    const float* __restrict__ esum, const float* __restrict__ embed_avg,
    const float* __restrict__ csnorm, float* __restrict__ out_w,
    float* __restrict__ out_ea, int nplanes) {
  __shared__ float tile[32][33];
  int kb = blockIdx.x & 31;
  int db = blockIdx.x >> 5;
  int tx = threadIdx.x & 31, ty = threadIdx.x >> 5;
#pragma unroll
  for (int i = 0; i < 4; ++i) {
    int kl = ty + i * 8;
    float s = 0.f;
    for (int p = 0; p < nplanes; ++p)
      s += esum[((size_t)p * NK + kb * 32 + kl) * ND + db * 32 + tx];
    tile[kl][tx] = s;
  }
  __syncthreads();
#pragma unroll
  for (int i = 0; i < 4; ++i) {
    int d = db * 32 + ty + i * 8;
    int k = kb * 32 + tx;
    size_t idx = (size_t)d * NK + k;
    float nea = embed_avg[idx] * 0.99f + 0.01f * tile[tx][ty + i * 8];
    out_ea[idx] = nea;
    out_w[idx] = nea / csnorm[k];
  }
}

// ---------------- kernel 8: hist EMA ----------------
__global__ __launch_bounds__(256) void hist_kernel(const float* __restrict__ hist,
                                                   const float* __restrict__ bhist,
                                                   float* __restrict__ out_hist) {
  int i = blockIdx.x * 256 + threadIdx.x;
  out_hist[i] = hist[i] * 0.99f + 0.01f * bhist[i];
}

extern "C" void kernel_launch(void* const* d_in, const int* in_sizes, int n_in,
                              void* d_out, int out_size, void* d_ws, size_t ws_size,
                              hipStream_t stream) {
  const float* X = (const float*)d_in[0];
  const int* keys = (const int*)d_in[1];
  const float* W = (const float*)d_in[2];
  const float* cluster_size = (const float*)d_in[3];
  const float* embed_avg = (const float*)d_in[4];
  const float* hist = (const float*)d_in[5];

  float* wsf = (float*)d_ws;
  int* wsi = (int*)d_ws;
  int* counts = wsi + OFF_COUNTS;
  int* cursor = wsi + OFF_CURSOR;
  float* bhist = wsf + OFF_BHIST;
  int* flagCnt = wsi + OFF_FLAGCNT;
  float* wsq = wsf + OFF_WSQ;
  int* flagList = wsi + OFF_FLAGLIST;
  float* csnorm = wsf + OFF_CSNORM;
  int* offsets = wsi + OFF_OFFSETS;
  int* argmin_i = wsi + OFF_ARGMIN;
  int* order = wsi + OFF_ORDER;
  u16* Wthi = (u16*)(wsf + OFF_WTHI);
  u16* Wtlo = (u16*)(wsf + OFF_WTLO);
  float* Wt32 = wsf + OFF_WT32;
  float* esum = wsf + OFF_ESUM;

  float* out = (float*)d_out;
  float* out_w = out;
  float* out_ncs = out + (size_t)ND * NK;
  float* out_ea = out_ncs + NK;
  float* out_hist = out_ea + (size_t)ND * NK;
  float* out_arg = out_hist + (size_t)NK * NC;

  const bool planes = ws_size >= WS_NEED_A;

  hipMemsetAsync(d_ws, 0, (size_t)OFF_ZERO_END * 4, stream);
  if (!planes)
    hipMemsetAsync(esum, 0, (size_t)NK * ND * 4, stream);

  prep_w<<<512, 256, 0, stream>>>(W, Wthi, Wtlo, Wt32, wsq);
  argmin_mfma<<<NB / 128, 256, 0, stream>>>(X, Wthi, Wtlo, wsq, keys, argmin_i,
                                            out_arg, counts, bhist, flagCnt,
                                            flagList);
  fixup_kernel<<<128, 256, 0, stream>>>(X, Wt32, wsq, keys, flagCnt, flagList,
                                        argmin_i, out_arg, counts, bhist);
  scan_kernel<<<1, 1024, 0, stream>>>(counts, cluster_size, out_ncs, csnorm,
                                      offsets);
  reorder_kernel<<<NB / 256, 256, 0, stream>>>(argmin_i, offsets, cursor, order);
  if (planes)
    gather_planes<<<NK * 8, 256, 0, stream>>>(X, order, offsets, counts, esum);
  else
    gather_atomic<<<NK * 8, 256, 0, stream>>>(X, order, offsets, counts, esum);
  ema_embed_kernel<<<(NK / 32) * (ND / 32), 256, 0, stream>>>(
      esum, embed_avg, csnorm, out_w, out_ea, planes ? 8 : 1);
  hist_kernel<<<(NK * NC) / 256, 256, 0, stream>>>(hist, bhist, out_hist);
}